// Round 5
// baseline (134.818 us; speedup 1.0000x reference)
//
#include <hip/hip_runtime.h>
#include <hip/hip_bf16.h>

// GRU cell v5: wave tile 32x64 (fa=2, fb=4) -> halves LDS A-read traffic per MFMA,
// same acc regs (32). 8 waves (2 wr x 4 wc) per 64-row block; waves sharing wc read
// identical B streams (L1 reuse). Fragment-major B (coalesced 1KB wave loads),
// barrier-free K-loops, padded LDS A tiles (LDW=264). 1024 blocks x 512 threads.

typedef __attribute__((ext_vector_type(8))) short s8v;           // 8 bf16 = 4 VGPR
typedef __attribute__((ext_vector_type(8))) unsigned short us8;
typedef __attribute__((ext_vector_type(4))) float f32x4;
typedef __attribute__((ext_vector_type(4))) float f4v;

#define LDW 264   // LDS row stride in shorts (528 B): breaks power-of-2 bank alias

__device__ __forceinline__ float bf2f(unsigned short u) {
  union { unsigned int i; float f; } c; c.i = ((unsigned int)u) << 16; return c.f;
}
__device__ __forceinline__ unsigned short f2bf(float f) {
  union { float f; unsigned int i; } c; c.f = f;
  return (unsigned short)((c.i + 0x7fffu + ((c.i >> 16) & 1u)) >> 16);  // RNE
}
__device__ __forceinline__ unsigned int pack2(float lo, float hi) {
  return (unsigned int)f2bf(lo) | ((unsigned int)f2bf(hi) << 16);
}
__device__ __forceinline__ float sig_(float s)  { return 1.0f / (1.0f + __expf(-s)); }
__device__ __forceinline__ float tanh_(float s) { return 2.0f / (1.0f + __expf(-2.0f * s)) - 1.0f; }

// ---------------- weight prep: fp32 [K][N] -> bf16 fragment-major tiles ----------------
// Tile (nt, kt) = 16 n x 32 k = 512 shorts (1 KB), lane-major:
//   n = nt*16 + (lane&15), k = kt*32 + (lane>>4)*8 + e ; tile order t = nt*16 + kt.
// wzr: nt 0..15 = Wz/Uz, nt 16..31 = Wr/Ur (k<256 -> W, else U). whh: nt 0..15 = Wh/Uh.
__global__ void gru_prep(const float* __restrict__ Wz, const float* __restrict__ Uz,
                         const float* __restrict__ Wr, const float* __restrict__ Ur,
                         const float* __restrict__ Wh, const float* __restrict__ Uh,
                         unsigned short* __restrict__ wzr, unsigned short* __restrict__ whh) {
  int idx = blockIdx.x * 256 + threadIdx.x;
  if (idx < 512 * 512) {
    int t = idx >> 9, lane = (idx >> 3) & 63, e = idx & 7;
    int nt = t >> 4, kt = t & 15;
    int n = nt * 16 + (lane & 15);
    int k = kt * 32 + ((lane >> 4) << 3) + e;
    int nn = n & 255;
    float v;
    if (n < 256) v = (k < 256) ? Wz[k * 256 + nn] : Uz[(k - 256) * 256 + nn];
    else         v = (k < 256) ? Wr[k * 256 + nn] : Ur[(k - 256) * 256 + nn];
    wzr[idx] = f2bf(v);
  } else if (idx < 512 * 512 + 256 * 512) {
    int j = idx - 512 * 512;
    int t = j >> 9, lane = (j >> 3) & 63, e = j & 7;
    int nt = t >> 4, kt = t & 15;
    int n = nt * 16 + (lane & 15);
    int k = kt * 32 + ((lane >> 4) << 3) + e;
    float v = (k < 256) ? Wh[k * 256 + n] : Uh[(k - 256) * 256 + n];
    whh[j] = f2bf(v);
  }
}

// ---- one K=256 chunk: B tiles coalesced from L2/L1, A from LDS; NO barriers ----
// acc[fa][fb]: fa = 2 row-frags (32 rows), fb = 4 col-frags (64 cols/wave).
__device__ __forceinline__ void gemm256(f32x4 acc[2][4],
    const unsigned short* __restrict__ Bsrc, int kt0,
    const unsigned short* A_lds, int wr, int wc, int l15, int lg4, int lane) {
  const unsigned short* bp  = Bsrc + (((wc * 64) + kt0) << 9) + lane * 8;  // nt=wc*4+fb
  const unsigned short* ap0 = A_lds + (wr * 32 + l15) * LDW + lg4 * 8;
#pragma unroll
  for (int kc = 0; kc < 8; ++kc) {
    s8v bq[4], af[2];
#pragma unroll
    for (int fb = 0; fb < 4; ++fb)
      bq[fb] = *(const s8v*)(bp + fb * 8192 + kc * 512);   // fb stride = 16 tiles
#pragma unroll
    for (int fa = 0; fa < 2; ++fa)
      af[fa] = *(const s8v*)(ap0 + fa * (16 * LDW) + kc * 32);
#pragma unroll
    for (int fa = 0; fa < 2; ++fa)
#pragma unroll
      for (int fb = 0; fb < 4; ++fb)
        acc[fa][fb] = __builtin_amdgcn_mfma_f32_16x16x32_bf16(af[fa], bq[fb], acc[fa][fb], 0, 0, 0);
  }
}

// ---------------- main fused kernel: 64 rows per block, 8 waves (2x4) ----------------
__global__ __launch_bounds__(512, 2) void gru_main(
    const float* __restrict__ x, const float* __restrict__ hp,
    const unsigned short* __restrict__ wzr, const unsigned short* __restrict__ whh,
    const float* __restrict__ bz, const float* __restrict__ br, const float* __restrict__ bh,
    float* __restrict__ out)
{
  __shared__ __align__(16) unsigned short x_l[64 * LDW];   // 33.8 KB
  __shared__ __align__(16) unsigned short h_l[64 * LDW];   // 33.8 KB

  const int tid = threadIdx.x;
  const int lane = tid & 63;
  const int wv = tid >> 6;
  const int wr = wv >> 2;                    // 0..1 : 32-row slice
  const int wc = wv & 3;                     // 0..3 : 64-col slice
  const int l15 = lane & 15, lg4 = lane >> 4;
  const int blk = blockIdx.x;
  const int row0 = blk * 64;

  // ---- stage x, h tiles to LDS (fp32 -> bf16); 32 cols per thread
  {
    const int srow = tid >> 3;               // 0..63
    const int part = tid & 7;                // 32-col eighth
    const float* xs = x  + (size_t)(row0 + srow) * 256 + part * 32;
    const float* hs = hp + (size_t)(row0 + srow) * 256 + part * 32;
    unsigned short* xd = x_l + srow * LDW + part * 32;
    unsigned short* hd = h_l + srow * LDW + part * 32;
#pragma unroll
    for (int j = 0; j < 4; ++j) {
      f4v v0 = *(const f4v*)(xs + j * 8);
      f4v v1 = *(const f4v*)(xs + j * 8 + 4);
      us8 o;
      o[0]=f2bf(v0[0]); o[1]=f2bf(v0[1]); o[2]=f2bf(v0[2]); o[3]=f2bf(v0[3]);
      o[4]=f2bf(v1[0]); o[5]=f2bf(v1[1]); o[6]=f2bf(v1[2]); o[7]=f2bf(v1[3]);
      *(us8*)(xd + j * 8) = o;
    }
#pragma unroll
    for (int j = 0; j < 4; ++j) {
      f4v v0 = *(const f4v*)(hs + j * 8);
      f4v v1 = *(const f4v*)(hs + j * 8 + 4);
      us8 o;
      o[0]=f2bf(v0[0]); o[1]=f2bf(v0[1]); o[2]=f2bf(v0[2]); o[3]=f2bf(v0[3]);
      o[4]=f2bf(v1[0]); o[5]=f2bf(v1[1]); o[6]=f2bf(v1[2]); o[7]=f2bf(v1[3]);
      *(us8*)(hd + j * 8) = o;
    }
  }
  __syncthreads();

  f32x4 acc[2][4];
  unsigned int zp[2][4][2];    // z gate, packed bf16 (rows 2p,2p+1)  : 16 VGPR
  unsigned int rhp[2][4][2];   // r*h, packed bf16                     : 16 VGPR

  // ===== PASS z: z = sigmoid(x Wz + h Uz + bz) -> regs (packed)
#pragma unroll
  for (int fa = 0; fa < 2; ++fa)
#pragma unroll
    for (int fb = 0; fb < 4; ++fb) acc[fa][fb] = (f32x4){0.f,0.f,0.f,0.f};
  gemm256(acc, wzr, 0, x_l, wr, wc, l15, lg4, lane);
  gemm256(acc, wzr, 8, h_l, wr, wc, l15, lg4, lane);
#pragma unroll
  for (int fb = 0; fb < 4; ++fb) {
    float bv = bz[wc * 64 + fb * 16 + l15];
#pragma unroll
    for (int fa = 0; fa < 2; ++fa) {
      f32x4 a = acc[fa][fb];
#pragma unroll
      for (int p = 0; p < 2; ++p)
        zp[fa][fb][p] = pack2(sig_(a[2 * p] + bv), sig_(a[2 * p + 1] + bv));
    }
  }

  // ===== PASS r: r = sigmoid(x Wr + h Ur + br); rh = r*h_prev -> regs (packed)
#pragma unroll
  for (int fa = 0; fa < 2; ++fa)
#pragma unroll
    for (int fb = 0; fb < 4; ++fb) acc[fa][fb] = (f32x4){0.f,0.f,0.f,0.f};
  gemm256(acc, wzr + 131072, 0, x_l, wr, wc, l15, lg4, lane);   // r tiles: nt 16..31
  gemm256(acc, wzr + 131072, 8, h_l, wr, wc, l15, lg4, lane);
#pragma unroll
  for (int fb = 0; fb < 4; ++fb) {
    float bv = br[wc * 64 + fb * 16 + l15];
    int col = wc * 64 + fb * 16 + l15;
#pragma unroll
    for (int fa = 0; fa < 2; ++fa) {
      f32x4 a = acc[fa][fb];
#pragma unroll
      for (int p = 0; p < 2; ++p) {
        int row = wr * 32 + fa * 16 + lg4 * 4 + 2 * p;
        float r0 = sig_(a[2 * p]     + bv);
        float r1 = sig_(a[2 * p + 1] + bv);
        float h0 = bf2f(h_l[row * LDW + col]);
        float h1 = bf2f(h_l[(row + 1) * LDW + col]);
        rhp[fa][fb][p] = pack2(r0 * h0, r1 * h1);
      }
    }
  }

  // ===== PASS h: h_hat = tanh(x Wh + rh Uh + bh)
#pragma unroll
  for (int fa = 0; fa < 2; ++fa)
#pragma unroll
    for (int fb = 0; fb < 4; ++fb) acc[fa][fb] = (f32x4){0.f,0.f,0.f,0.f};
  gemm256(acc, whh, 0, x_l, wr, wc, l15, lg4, lane);   // x-chunk (x_l still valid)

  __syncthreads();                            // all waves done reading x_l
  // overwrite x_l with rh (each (row,col) written by exactly one thread)
#pragma unroll
  for (int fb = 0; fb < 4; ++fb) {
    int col = wc * 64 + fb * 16 + l15;
#pragma unroll
    for (int fa = 0; fa < 2; ++fa)
#pragma unroll
      for (int p = 0; p < 2; ++p) {
        int row = wr * 32 + fa * 16 + lg4 * 4 + 2 * p;
        unsigned int w = rhp[fa][fb][p];
        x_l[row * LDW + col]       = (unsigned short)(w & 0xffffu);
        x_l[(row + 1) * LDW + col] = (unsigned short)(w >> 16);
      }
  }
  __syncthreads();                            // rh visible to all waves

  gemm256(acc, whh, 8, x_l, wr, wc, l15, lg4, lane);   // rh-chunk

  // ===== epilogue: h = z*h_prev + (1-z)*h_hat
#pragma unroll
  for (int fb = 0; fb < 4; ++fb) {
    float bv = bh[wc * 64 + fb * 16 + l15];
    int col = wc * 64 + fb * 16 + l15;
#pragma unroll
    for (int fa = 0; fa < 2; ++fa) {
      f32x4 a = acc[fa][fb];
#pragma unroll
      for (int i = 0; i < 4; ++i) {
        int row = wr * 32 + fa * 16 + lg4 * 4 + i;
        float hh = tanh_(a[i] + bv);
        unsigned int zw = zp[fa][fb][i >> 1];
        float z = bf2f((unsigned short)((i & 1) ? (zw >> 16) : (zw & 0xffffu)));
        float hv = bf2f(h_l[row * LDW + col]);
        out[(size_t)(row0 + row) * 256 + col] = z * hv + (1.0f - z) * hh;
      }
    }
  }
}

extern "C" void kernel_launch(void* const* d_in, const int* in_sizes, int n_in,
                              void* d_out, int out_size, void* d_ws, size_t ws_size,
                              hipStream_t stream) {
  const float* x  = (const float*)d_in[0];
  const float* hp = (const float*)d_in[1];
  const float* Wz = (const float*)d_in[2];
  const float* Uz = (const float*)d_in[3];
  const float* bz = (const float*)d_in[4];
  const float* Wr = (const float*)d_in[5];
  const float* Ur = (const float*)d_in[6];
  const float* br = (const float*)d_in[7];
  const float* Wh = (const float*)d_in[8];
  const float* Uh = (const float*)d_in[9];
  const float* bh = (const float*)d_in[10];

  if (ws_size < (size_t)(512 * 512 + 256 * 512) * sizeof(unsigned short)) return;  // need 768 KB

  unsigned short* wzr = (unsigned short*)d_ws;
  unsigned short* whh = wzr + 512 * 512;

  gru_prep<<<1536, 256, 0, stream>>>(Wz, Uz, Wr, Ur, Wh, Uh, wzr, whh);
  gru_main<<<1024, 512, 0, stream>>>(x, hp, wzr, whh, bz, br, bh, (float*)d_out);
}

// Round 6
// 112.221 us; speedup vs baseline: 1.2014x; 1.2014x over previous
//
#include <hip/hip_runtime.h>
#include <hip/hip_bf16.h>

// GRU cell v6: wave-private B staging via global_load_lds (DMA, zero VGPR cost),
// ring-3 LDS buffers pipelined with s_waitcnt vmcnt(2). No block barriers in K-loops.
// v4 geometry: 64-row blocks, 8 waves, wave tile 64x32 (fa=4, fb=2), persistent regs 64.
// Fragment-major weights (1KB tiles, lane-major) -> one dwordx4 DMA per tile per wave.

typedef __attribute__((ext_vector_type(8))) short s8v;           // 8 bf16 = 4 VGPR
typedef __attribute__((ext_vector_type(8))) unsigned short us8;
typedef __attribute__((ext_vector_type(4))) float f32x4;
typedef __attribute__((ext_vector_type(4))) float f4v;

#define LDW 264   // LDS row stride in shorts (528 B, 16B-aligned rows)

__device__ __forceinline__ float bf2f(unsigned short u) {
  union { unsigned int i; float f; } c; c.i = ((unsigned int)u) << 16; return c.f;
}
__device__ __forceinline__ unsigned short f2bf(float f) {
  union { float f; unsigned int i; } c; c.f = f;
  return (unsigned short)((c.i + 0x7fffu + ((c.i >> 16) & 1u)) >> 16);  // RNE
}
__device__ __forceinline__ unsigned int pack2(float lo, float hi) {
  return (unsigned int)f2bf(lo) | ((unsigned int)f2bf(hi) << 16);
}
__device__ __forceinline__ float sig_(float s)  { return 1.0f / (1.0f + __expf(-s)); }
__device__ __forceinline__ float tanh_(float s) { return 2.0f / (1.0f + __expf(-2.0f * s)) - 1.0f; }

// async global(16B/lane) -> LDS(lane-linear). dst must be wave-uniform; src per-lane.
__device__ __forceinline__ void dma16(const unsigned short* src_lane, unsigned short* dst_uniform) {
  __builtin_amdgcn_global_load_lds(
      (const __attribute__((address_space(1))) void*)src_lane,
      (__attribute__((address_space(3))) void*)dst_uniform, 16, 0, 0);
}

// ---------------- weight prep: fp32 [K][N] -> bf16 fragment-major tiles ----------------
// Tile (nt, kt) = 16 n x 32 k = 512 shorts (1 KB), lane-major:
//   n = nt*16 + (lane&15), k = kt*32 + (lane>>4)*8 + e ; tile index t = nt*16 + kt.
// wzr: nt 0..15 = Wz/Uz, nt 16..31 = Wr/Ur (k<256 -> W, else U). whh: nt 0..15 = Wh/Uh.
__global__ void gru_prep(const float* __restrict__ Wz, const float* __restrict__ Uz,
                         const float* __restrict__ Wr, const float* __restrict__ Ur,
                         const float* __restrict__ Wh, const float* __restrict__ Uh,
                         unsigned short* __restrict__ wzr, unsigned short* __restrict__ whh) {
  int idx = blockIdx.x * 256 + threadIdx.x;
  if (idx < 512 * 512) {
    int t = idx >> 9, lane = (idx >> 3) & 63, e = idx & 7;
    int nt = t >> 4, kt = t & 15;
    int n = nt * 16 + (lane & 15);
    int k = kt * 32 + ((lane >> 4) << 3) + e;
    int nn = n & 255;
    float v;
    if (n < 256) v = (k < 256) ? Wz[k * 256 + nn] : Uz[(k - 256) * 256 + nn];
    else         v = (k < 256) ? Wr[k * 256 + nn] : Ur[(k - 256) * 256 + nn];
    wzr[idx] = f2bf(v);
  } else if (idx < 512 * 512 + 256 * 512) {
    int j = idx - 512 * 512;
    int t = j >> 9, lane = (j >> 3) & 63, e = j & 7;
    int nt = t >> 4, kt = t & 15;
    int n = nt * 16 + (lane & 15);
    int k = kt * 32 + ((lane >> 4) << 3) + e;
    float v = (k < 256) ? Wh[k * 256 + n] : Uh[(k - 256) * 256 + n];
    whh[j] = f2bf(v);
  }
}

// ---- one K=256 chunk: B DMA'd to wave-private ring-3 LDS, A from LDS; no barriers ----
// Bt = weight base + (wv*32 + kt0)*512 + lane*8  (lane offset included).
// Bw = &Bs[wv][0][0][0] viewed as [3][2][512].
__device__ __forceinline__ void gemm256(f32x4 acc[4][2],
    const unsigned short* __restrict__ Bt,
    const unsigned short* A_lds,
    unsigned short (*Bw)[2][512],
    int l15, int lg4, int lane)
{
  // prologue: slot 0 <- kc 0
  dma16(Bt,        &Bw[0][0][0]);
  dma16(Bt + 8192, &Bw[0][1][0]);
#pragma unroll
  for (int kc = 0; kc < 8; ++kc) {
    if (kc < 7) {
      const unsigned short* s = Bt + (kc + 1) * 512;
      const int sl = (kc + 1) % 3;
      dma16(s,        &Bw[sl][0][0]);
      dma16(s + 8192, &Bw[sl][1][0]);
      asm volatile("s_waitcnt vmcnt(2)" ::: "memory");   // kc's pair done, next pair in flight
    } else {
      asm volatile("s_waitcnt vmcnt(0)" ::: "memory");
    }
    __builtin_amdgcn_sched_barrier(0);
    const int cs = kc % 3;
    s8v bq0 = *(const s8v*)(&Bw[cs][0][lane * 8]);
    s8v bq1 = *(const s8v*)(&Bw[cs][1][lane * 8]);
    const unsigned short* ap = A_lds + l15 * LDW + kc * 32 + lg4 * 8;
    s8v af[4];
#pragma unroll
    for (int fa = 0; fa < 4; ++fa)
      af[fa] = *(const s8v*)(ap + fa * (16 * LDW));
#pragma unroll
    for (int fa = 0; fa < 4; ++fa) {
      acc[fa][0] = __builtin_amdgcn_mfma_f32_16x16x32_bf16(af[fa], bq0, acc[fa][0], 0, 0, 0);
      acc[fa][1] = __builtin_amdgcn_mfma_f32_16x16x32_bf16(af[fa], bq1, acc[fa][1], 0, 0, 0);
    }
  }
}

// ---------------- main fused kernel: 64 rows per block, 8 waves ----------------
__global__ __launch_bounds__(512, 2) void gru_main(
    const float* __restrict__ x, const float* __restrict__ hp,
    const unsigned short* __restrict__ wzr, const unsigned short* __restrict__ whh,
    const float* __restrict__ bz, const float* __restrict__ br, const float* __restrict__ bh,
    float* __restrict__ out)
{
  __shared__ __align__(16) unsigned short x_l[64 * LDW];       // 33.8 KB
  __shared__ __align__(16) unsigned short h_l[64 * LDW];       // 33.8 KB
  __shared__ __align__(16) unsigned short Bs[8][3][2][512];    // 48 KB wave-private rings

  const int tid = threadIdx.x;
  const int lane = tid & 63;
  const int wv = tid >> 6;                   // 0..7 : wave's 32-col slice
  const int l15 = lane & 15, lg4 = lane >> 4;
  const int blk = blockIdx.x;
  const int row0 = blk * 64;

  unsigned short (*Bw)[2][512] = (unsigned short (*)[2][512])&Bs[wv][0][0][0];

  // ---- stage x, h tiles to LDS (fp32 -> bf16); 32 cols per thread
  {
    const int srow = tid >> 3;               // 0..63
    const int part = tid & 7;                // 32-col eighth
    const float* xs = x  + (size_t)(row0 + srow) * 256 + part * 32;
    const float* hs = hp + (size_t)(row0 + srow) * 256 + part * 32;
    unsigned short* xd = x_l + srow * LDW + part * 32;
    unsigned short* hd = h_l + srow * LDW + part * 32;
#pragma unroll
    for (int j = 0; j < 4; ++j) {
      f4v v0 = *(const f4v*)(xs + j * 8);
      f4v v1 = *(const f4v*)(xs + j * 8 + 4);
      us8 o;
      o[0]=f2bf(v0[0]); o[1]=f2bf(v0[1]); o[2]=f2bf(v0[2]); o[3]=f2bf(v0[3]);
      o[4]=f2bf(v1[0]); o[5]=f2bf(v1[1]); o[6]=f2bf(v1[2]); o[7]=f2bf(v1[3]);
      *(us8*)(xd + j * 8) = o;
    }
#pragma unroll
    for (int j = 0; j < 4; ++j) {
      f4v v0 = *(const f4v*)(hs + j * 8);
      f4v v1 = *(const f4v*)(hs + j * 8 + 4);
      us8 o;
      o[0]=f2bf(v0[0]); o[1]=f2bf(v0[1]); o[2]=f2bf(v0[2]); o[3]=f2bf(v0[3]);
      o[4]=f2bf(v1[0]); o[5]=f2bf(v1[1]); o[6]=f2bf(v1[2]); o[7]=f2bf(v1[3]);
      *(us8*)(hd + j * 8) = o;
    }
  }
  __syncthreads();

  f32x4 acc[4][2];
  unsigned int zp[4][2][2];    // z gate, packed bf16 (rows 2p,2p+1)  : 16 VGPR
  unsigned int rhp[4][2][2];   // r*h_prev, packed bf16                : 16 VGPR

  // ===== PASS z: z = sigmoid(x Wz + h Uz + bz) -> regs (packed)
#pragma unroll
  for (int fa = 0; fa < 4; ++fa)
#pragma unroll
    for (int fb = 0; fb < 2; ++fb) acc[fa][fb] = (f32x4){0.f,0.f,0.f,0.f};
  gemm256(acc, wzr + (wv * 32 + 0) * 512 + lane * 8, x_l, Bw, l15, lg4, lane);
  gemm256(acc, wzr + (wv * 32 + 8) * 512 + lane * 8, h_l, Bw, l15, lg4, lane);
#pragma unroll
  for (int fb = 0; fb < 2; ++fb) {
    float bv = bz[wv * 32 + fb * 16 + l15];
#pragma unroll
    for (int fa = 0; fa < 4; ++fa) {
      f32x4 a = acc[fa][fb];
#pragma unroll
      for (int p = 0; p < 2; ++p)
        zp[fa][fb][p] = pack2(sig_(a[2 * p] + bv), sig_(a[2 * p + 1] + bv));
    }
  }

  // ===== PASS r: r = sigmoid(x Wr + h Ur + br); rh = r*h_prev -> regs (packed)
#pragma unroll
  for (int fa = 0; fa < 4; ++fa)
#pragma unroll
    for (int fb = 0; fb < 2; ++fb) acc[fa][fb] = (f32x4){0.f,0.f,0.f,0.f};
  gemm256(acc, wzr + 131072 + (wv * 32 + 0) * 512 + lane * 8, x_l, Bw, l15, lg4, lane);
  gemm256(acc, wzr + 131072 + (wv * 32 + 8) * 512 + lane * 8, h_l, Bw, l15, lg4, lane);
#pragma unroll
  for (int fb = 0; fb < 2; ++fb) {
    float bv = br[wv * 32 + fb * 16 + l15];
    int col = wv * 32 + fb * 16 + l15;
#pragma unroll
    for (int fa = 0; fa < 4; ++fa) {
      f32x4 a = acc[fa][fb];
#pragma unroll
      for (int p = 0; p < 2; ++p) {
        int row = fa * 16 + lg4 * 4 + 2 * p;
        float r0 = sig_(a[2 * p]     + bv);
        float r1 = sig_(a[2 * p + 1] + bv);
        float h0 = bf2f(h_l[row * LDW + col]);
        float h1 = bf2f(h_l[(row + 1) * LDW + col]);
        rhp[fa][fb][p] = pack2(r0 * h0, r1 * h1);
      }
    }
  }

  // ===== PASS h: h_hat = tanh(x Wh + rh Uh + bh)
#pragma unroll
  for (int fa = 0; fa < 4; ++fa)
#pragma unroll
    for (int fb = 0; fb < 2; ++fb) acc[fa][fb] = (f32x4){0.f,0.f,0.f,0.f};
  gemm256(acc, whh + (wv * 32 + 0) * 512 + lane * 8, x_l, Bw, l15, lg4, lane);

  __syncthreads();                            // all waves done reading x_l
  // overwrite x_l with rh (each (row,col) written by exactly one thread)
#pragma unroll
  for (int fb = 0; fb < 2; ++fb) {
    int col = wv * 32 + fb * 16 + l15;
#pragma unroll
    for (int fa = 0; fa < 4; ++fa)
#pragma unroll
      for (int p = 0; p < 2; ++p) {
        int row = fa * 16 + lg4 * 4 + 2 * p;
        unsigned int w = rhp[fa][fb][p];
        x_l[row * LDW + col]       = (unsigned short)(w & 0xffffu);
        x_l[(row + 1) * LDW + col] = (unsigned short)(w >> 16);
      }
  }
  __syncthreads();                            // rh visible to all waves

  gemm256(acc, whh + (wv * 32 + 8) * 512 + lane * 8, x_l, Bw, l15, lg4, lane);

  // ===== epilogue: h = z*h_prev + (1-z)*h_hat
#pragma unroll
  for (int fb = 0; fb < 2; ++fb) {
    float bv = bh[wv * 32 + fb * 16 + l15];
    int col = wv * 32 + fb * 16 + l15;
#pragma unroll
    for (int fa = 0; fa < 4; ++fa) {
      f32x4 a = acc[fa][fb];
#pragma unroll
      for (int i = 0; i < 4; ++i) {
        int row = fa * 16 + lg4 * 4 + i;
        float hh = tanh_(a[i] + bv);
        unsigned int zw = zp[fa][fb][i >> 1];
        float z = bf2f((unsigned short)((i & 1) ? (zw >> 16) : (zw & 0xffffu)));
        float hv = bf2f(h_l[row * LDW + col]);
        out[(size_t)(row0 + row) * 256 + col] = z * hv + (1.0f - z) * hh;
      }
    }
  }
}

extern "C" void kernel_launch(void* const* d_in, const int* in_sizes, int n_in,
                              void* d_out, int out_size, void* d_ws, size_t ws_size,
                              hipStream_t stream) {
  const float* x  = (const float*)d_in[0];
  const float* hp = (const float*)d_in[1];
  const float* Wz = (const float*)d_in[2];
  const float* Uz = (const float*)d_in[3];
  const float* bz = (const float*)d_in[4];
  const float* Wr = (const float*)d_in[5];
  const float* Ur = (const float*)d_in[6];
  const float* br = (const float*)d_in[7];
  const float* Wh = (const float*)d_in[8];
  const float* Uh = (const float*)d_in[9];
  const float* bh = (const float*)d_in[10];

  if (ws_size < (size_t)(512 * 512 + 256 * 512) * sizeof(unsigned short)) return;  // need 768 KB

  unsigned short* wzr = (unsigned short*)d_ws;
  unsigned short* whh = wzr + 512 * 512;

  gru_prep<<<1536, 256, 0, stream>>>(Wz, Uz, Wr, Ur, Wh, Uh, wzr, whh);
  gru_main<<<1024, 512, 0, stream>>>(x, hp, wzr, whh, bz, br, bh, (float*)d_out);
}

// Round 7
// 106.221 us; speedup vs baseline: 1.2692x; 1.0565x over previous
//
#include <hip/hip_runtime.h>
#include <hip/hip_bf16.h>

// GRU cell v7: fused z+r K-sweep (shared A-frags), deep DMA pipeline
// (2-tile groups, prefetch distance 3, ring-4, vmcnt(6)), XOR-swizzled
// unpadded LDS A tiles (conflict-free b128 reads). 64-row blocks, 8 waves,
// wave tile 64x32 (fa=4, fb=2). LDS 128 KB. Weights fragment-major in d_ws.

typedef __attribute__((ext_vector_type(8))) short s8v;           // 8 bf16 = 4 VGPR
typedef __attribute__((ext_vector_type(8))) unsigned short us8;
typedef __attribute__((ext_vector_type(4))) float f32x4;
typedef __attribute__((ext_vector_type(4))) float f4v;

__device__ __forceinline__ float bf2f(unsigned short u) {
  union { unsigned int i; float f; } c; c.i = ((unsigned int)u) << 16; return c.f;
}
__device__ __forceinline__ unsigned short f2bf(float f) {
  union { float f; unsigned int i; } c; c.f = f;
  return (unsigned short)((c.i + 0x7fffu + ((c.i >> 16) & 1u)) >> 16);  // RNE
}
__device__ __forceinline__ unsigned int pack2(float lo, float hi) {
  return (unsigned int)f2bf(lo) | ((unsigned int)f2bf(hi) << 16);
}
__device__ __forceinline__ float sig_(float s)  { return 1.0f / (1.0f + __expf(-s)); }
__device__ __forceinline__ float tanh_(float s) { return 2.0f / (1.0f + __expf(-2.0f * s)) - 1.0f; }

// async global(16B/lane) -> LDS(lane-linear). dst wave-uniform; src per-lane.
__device__ __forceinline__ void dma16(const unsigned short* src_lane, unsigned short* dst_uniform) {
  __builtin_amdgcn_global_load_lds(
      (const __attribute__((address_space(1))) void*)src_lane,
      (__attribute__((address_space(3))) void*)dst_uniform, 16, 0, 0);
}

// swizzled LDS A-tile accessors: row-major [64][256] shorts, granule (16B=8sh)
// index XOR'd with (row&7) -> 2-lane/bank (free) for both b128 frag reads & writes.
__device__ __forceinline__ float ldsA_get(const unsigned short* A, int row, int col) {
  int gp = ((col >> 3) ^ (row & 7));
  return bf2f(A[row * 256 + gp * 8 + (col & 7)]);
}
__device__ __forceinline__ void ldsA_put(unsigned short* A, int row, int col, unsigned short v) {
  int gp = ((col >> 3) ^ (row & 7));
  A[row * 256 + gp * 8 + (col & 7)] = v;
}

// ---------------- weight prep: fp32 [K][N] -> bf16 fragment-major tiles ----------------
// Tile (nt, kt) = 16 n x 32 k = 512 shorts (1 KB), lane-major:
//   n = nt*16 + (lane&15), k = kt*32 + (lane>>4)*8 + e ; tile index t = nt*16 + kt.
// wzr: nt 0..15 = Wz/Uz, nt 16..31 = Wr/Ur (k<256 -> W, else U). whh: nt 0..15 = Wh/Uh.
__global__ void gru_prep(const float* __restrict__ Wz, const float* __restrict__ Uz,
                         const float* __restrict__ Wr, const float* __restrict__ Ur,
                         const float* __restrict__ Wh, const float* __restrict__ Uh,
                         unsigned short* __restrict__ wzr, unsigned short* __restrict__ whh) {
  int idx = blockIdx.x * 256 + threadIdx.x;
  if (idx < 512 * 512) {
    int t = idx >> 9, lane = (idx >> 3) & 63, e = idx & 7;
    int nt = t >> 4, kt = t & 15;
    int n = nt * 16 + (lane & 15);
    int k = kt * 32 + ((lane >> 4) << 3) + e;
    int nn = n & 255;
    float v;
    if (n < 256) v = (k < 256) ? Wz[k * 256 + nn] : Uz[(k - 256) * 256 + nn];
    else         v = (k < 256) ? Wr[k * 256 + nn] : Ur[(k - 256) * 256 + nn];
    wzr[idx] = f2bf(v);
  } else if (idx < 512 * 512 + 256 * 512) {
    int j = idx - 512 * 512;
    int t = j >> 9, lane = (j >> 3) & 63, e = j & 7;
    int nt = t >> 4, kt = t & 15;
    int n = nt * 16 + (lane & 15);
    int k = kt * 32 + ((lane >> 4) << 3) + e;
    float v = (k < 256) ? Wh[k * 256 + n] : Uh[(k - 256) * 256 + n];
    whh[j] = f2bf(v);
  }
}

#define MFMA(a, b, c) __builtin_amdgcn_mfma_f32_16x16x32_bf16((a), (b), (c), 0, 0, 0)

// ---------------- main fused kernel: 64 rows per block, 8 waves ----------------
__global__ __launch_bounds__(512, 2) void gru_main(
    const float* __restrict__ x, const float* __restrict__ hp,
    const unsigned short* __restrict__ wzr, const unsigned short* __restrict__ whh,
    const float* __restrict__ bz, const float* __restrict__ br, const float* __restrict__ bh,
    float* __restrict__ out)
{
  __shared__ __align__(16) unsigned short x_l[64 * 256];       // 32 KB, XOR-swizzled
  __shared__ __align__(16) unsigned short h_l[64 * 256];       // 32 KB
  __shared__ __align__(16) unsigned short Bs[8][4][2][512];    // 64 KB wave-private ring-4

  const int tid = threadIdx.x;
  const int lane = tid & 63;
  const int wv = tid >> 6;                   // 0..7 : wave's 32-col slice
  const int l15 = lane & 15, lg4 = lane >> 4;
  const int blk = blockIdx.x;
  const int row0 = blk * 64;

  unsigned short (*ring)[2][512] = Bs[wv];
  const unsigned short* Bz = wzr + wv * 16384 + lane * 8;   // z tiles (nt=wv*2), +131072 for r
  const unsigned short* Bh = whh + wv * 16384 + lane * 8;

  // ---- prologue DMAs for zr sweep (overlap with staging; drained by barrier)
  // zr group g (0..31): kc = g>>1 ; g even -> z pair, g odd -> r pair.
#define ZR_SRC(g) (Bz + ((g) & 1) * 131072 + ((g) >> 1) * 512)
  {
    dma16(ZR_SRC(0), &ring[0][0][0]); dma16(ZR_SRC(0) + 8192, &ring[0][1][0]);
    dma16(ZR_SRC(1), &ring[1][0][0]); dma16(ZR_SRC(1) + 8192, &ring[1][1][0]);
    dma16(ZR_SRC(2), &ring[2][0][0]); dma16(ZR_SRC(2) + 8192, &ring[2][1][0]);
  }

  // ---- stage x, h tiles to LDS (fp32 -> bf16), granule-XOR layout
  {
    const int srow = tid >> 3;               // 0..63
    const int part = tid & 7;                // 4 granules each
    const float* xs = x  + (size_t)(row0 + srow) * 256 + part * 32;
    const float* hs = hp + (size_t)(row0 + srow) * 256 + part * 32;
    unsigned short* xd = x_l + srow * 256;
    unsigned short* hd = h_l + srow * 256;
    const int r7 = srow & 7;
#pragma unroll
    for (int j = 0; j < 4; ++j) {
      int gp = (part * 4 + j) ^ r7;
      f4v v0 = *(const f4v*)(xs + j * 8);
      f4v v1 = *(const f4v*)(xs + j * 8 + 4);
      us8 o;
      o[0]=f2bf(v0[0]); o[1]=f2bf(v0[1]); o[2]=f2bf(v0[2]); o[3]=f2bf(v0[3]);
      o[4]=f2bf(v1[0]); o[5]=f2bf(v1[1]); o[6]=f2bf(v1[2]); o[7]=f2bf(v1[3]);
      *(us8*)(xd + gp * 8) = o;
    }
#pragma unroll
    for (int j = 0; j < 4; ++j) {
      int gp = (part * 4 + j) ^ r7;
      f4v v0 = *(const f4v*)(hs + j * 8);
      f4v v1 = *(const f4v*)(hs + j * 8 + 4);
      us8 o;
      o[0]=f2bf(v0[0]); o[1]=f2bf(v0[1]); o[2]=f2bf(v0[2]); o[3]=f2bf(v0[3]);
      o[4]=f2bf(v1[0]); o[5]=f2bf(v1[1]); o[6]=f2bf(v1[2]); o[7]=f2bf(v1[3]);
      *(us8*)(hd + gp * 8) = o;
    }
  }
  __syncthreads();   // also drains the prologue DMAs

  f32x4 accz[4][2], accr[4][2];
#pragma unroll
  for (int fa = 0; fa < 4; ++fa)
#pragma unroll
    for (int fb = 0; fb < 2; ++fb) {
      accz[fa][fb] = (f32x4){0.f,0.f,0.f,0.f};
      accr[fa][fb] = (f32x4){0.f,0.f,0.f,0.f};
    }

  // ===== fused z+r sweep: 32 groups, A-frags shared between z (even) / r (odd)
  {
    s8v af[4];
#pragma unroll
    for (int g = 0; g < 32; ++g) {
      if (g < 29) {
        const unsigned short* s = ZR_SRC(g + 3);
        const int sl = (g + 3) & 3;
        dma16(s, &ring[sl][0][0]); dma16(s + 8192, &ring[sl][1][0]);
        asm volatile("s_waitcnt vmcnt(6)" ::: "memory");
      } else if (g == 29) { asm volatile("s_waitcnt vmcnt(4)" ::: "memory");
      } else if (g == 30) { asm volatile("s_waitcnt vmcnt(2)" ::: "memory");
      } else              { asm volatile("s_waitcnt vmcnt(0)" ::: "memory"); }
      __builtin_amdgcn_sched_barrier(0);
      const int cs = g & 3;
      s8v b0 = *(const s8v*)(&ring[cs][0][lane * 8]);
      s8v b1 = *(const s8v*)(&ring[cs][1][lane * 8]);
      if ((g & 1) == 0) {
        const int kc = g >> 1;
        const unsigned short* A = (kc < 8) ? x_l : h_l;
        const int kk = kc & 7;
#pragma unroll
        for (int fa = 0; fa < 4; ++fa) {
          int row = fa * 16 + l15;
          int gp = (kk * 4 + lg4) ^ (row & 7);
          af[fa] = *(const s8v*)(A + row * 256 + gp * 8);
        }
#pragma unroll
        for (int fa = 0; fa < 4; ++fa) {
          accz[fa][0] = MFMA(af[fa], b0, accz[fa][0]);
          accz[fa][1] = MFMA(af[fa], b1, accz[fa][1]);
        }
      } else {
#pragma unroll
        for (int fa = 0; fa < 4; ++fa) {
          accr[fa][0] = MFMA(af[fa], b0, accr[fa][0]);
          accr[fa][1] = MFMA(af[fa], b1, accr[fa][1]);
        }
      }
    }
  }

  // ===== z, r epilogues -> packed regs
  unsigned int zp[4][2][2];    // z gate                      : 16 VGPR
  unsigned int rhp[4][2][2];   // r*h_prev                    : 16 VGPR
#pragma unroll
  for (int fb = 0; fb < 2; ++fb) {
    const int col = wv * 32 + fb * 16 + l15;
    const float bvz = bz[col], bvr = br[col];
#pragma unroll
    for (int fa = 0; fa < 4; ++fa) {
      f32x4 az = accz[fa][fb], ar = accr[fa][fb];
#pragma unroll
      for (int p = 0; p < 2; ++p) {
        const int row = fa * 16 + lg4 * 4 + 2 * p;
        zp[fa][fb][p] = pack2(sig_(az[2*p] + bvz), sig_(az[2*p+1] + bvz));
        float r0 = sig_(ar[2*p]     + bvr);
        float r1 = sig_(ar[2*p+1]   + bvr);
        float h0 = ldsA_get(h_l, row,     col);
        float h1 = ldsA_get(h_l, row + 1, col);
        rhp[fa][fb][p] = pack2(r0 * h0, r1 * h1);
      }
    }
  }

  // ===== h sweep: 16 groups (kc 0..15); A = x_l (kc<8: x ; kc>=8: rh overwrite)
  f32x4 acch[4][2];
#pragma unroll
  for (int fa = 0; fa < 4; ++fa)
#pragma unroll
    for (int fb = 0; fb < 2; ++fb) acch[fa][fb] = (f32x4){0.f,0.f,0.f,0.f};
  {
    dma16(Bh,            &ring[0][0][0]); dma16(Bh + 8192,            &ring[0][1][0]);
    dma16(Bh + 512,      &ring[1][0][0]); dma16(Bh + 512 + 8192,      &ring[1][1][0]);
    dma16(Bh + 1024,     &ring[2][0][0]); dma16(Bh + 1024 + 8192,     &ring[2][1][0]);
#pragma unroll
    for (int g = 0; g < 16; ++g) {
      if (g == 8) {
        __syncthreads();                       // all waves done reading x half
#pragma unroll
        for (int fb = 0; fb < 2; ++fb) {
          const int col = wv * 32 + fb * 16 + l15;
#pragma unroll
          for (int fa = 0; fa < 4; ++fa)
#pragma unroll
            for (int p = 0; p < 2; ++p) {
              const int row = fa * 16 + lg4 * 4 + 2 * p;
              unsigned int w = rhp[fa][fb][p];
              ldsA_put(x_l, row,     col, (unsigned short)(w & 0xffffu));
              ldsA_put(x_l, row + 1, col, (unsigned short)(w >> 16));
            }
        }
        __syncthreads();                       // rh visible
      }
      if (g < 13) {
        const unsigned short* s = Bh + (g + 3) * 512;
        const int sl = (g + 3) & 3;
        dma16(s, &ring[sl][0][0]); dma16(s + 8192, &ring[sl][1][0]);
        asm volatile("s_waitcnt vmcnt(6)" ::: "memory");
      } else if (g == 13) { asm volatile("s_waitcnt vmcnt(4)" ::: "memory");
      } else if (g == 14) { asm volatile("s_waitcnt vmcnt(2)" ::: "memory");
      } else              { asm volatile("s_waitcnt vmcnt(0)" ::: "memory"); }
      __builtin_amdgcn_sched_barrier(0);
      const int cs = g & 3;
      s8v b0 = *(const s8v*)(&ring[cs][0][lane * 8]);
      s8v b1 = *(const s8v*)(&ring[cs][1][lane * 8]);
      const int kk = g & 7;
      s8v af[4];
#pragma unroll
      for (int fa = 0; fa < 4; ++fa) {
        int row = fa * 16 + l15;
        int gp = (kk * 4 + lg4) ^ (row & 7);
        af[fa] = *(const s8v*)(x_l + row * 256 + gp * 8);
      }
#pragma unroll
      for (int fa = 0; fa < 4; ++fa) {
        acch[fa][0] = MFMA(af[fa], b0, acch[fa][0]);
        acch[fa][1] = MFMA(af[fa], b1, acch[fa][1]);
      }
    }
  }

  // ===== epilogue: h = z*h_prev + (1-z)*h_hat
#pragma unroll
  for (int fb = 0; fb < 2; ++fb) {
    const int col = wv * 32 + fb * 16 + l15;
    const float bv = bh[col];
#pragma unroll
    for (int fa = 0; fa < 4; ++fa) {
      f32x4 a = acch[fa][fb];
#pragma unroll
      for (int i = 0; i < 4; ++i) {
        const int row = fa * 16 + lg4 * 4 + i;
        float hh = tanh_(a[i] + bv);
        unsigned int zw = zp[fa][fb][i >> 1];
        float z = bf2f((unsigned short)((i & 1) ? (zw >> 16) : (zw & 0xffffu)));
        float hv = ldsA_get(h_l, row, col);
        out[(size_t)(row0 + row) * 256 + col] = z * hv + (1.0f - z) * hh;
      }
    }
  }
}

extern "C" void kernel_launch(void* const* d_in, const int* in_sizes, int n_in,
                              void* d_out, int out_size, void* d_ws, size_t ws_size,
                              hipStream_t stream) {
  const float* x  = (const float*)d_in[0];
  const float* hp = (const float*)d_in[1];
  const float* Wz = (const float*)d_in[2];
  const float* Uz = (const float*)d_in[3];
  const float* bz = (const float*)d_in[4];
  const float* Wr = (const float*)d_in[5];
  const float* Ur = (const float*)d_in[6];
  const float* br = (const float*)d_in[7];
  const float* Wh = (const float*)d_in[8];
  const float* Uh = (const float*)d_in[9];
  const float* bh = (const float*)d_in[10];

  if (ws_size < (size_t)(512 * 512 + 256 * 512) * sizeof(unsigned short)) return;  // need 768 KB

  unsigned short* wzr = (unsigned short*)d_ws;
  unsigned short* whh = wzr + 512 * 512;

  gru_prep<<<1536, 256, 0, stream>>>(Wz, Uz, Wr, Ur, Wh, Uh, wzr, whh);
  gru_main<<<1024, 512, 0, stream>>>(x, hp, wzr, whh, bz, br, bh, (float*)d_out);
}

// Round 8
// 104.181 us; speedup vs baseline: 1.2941x; 1.0196x over previous
//
#include <hip/hip_runtime.h>
#include <hip/hip_bf16.h>

// GRU cell v8: B double-buffered in registers (distance-1, sched_barrier-fenced,
// 16 live VGPRs), unfused z/r/h sweeps (acc 32). LDS = x_l+h_l = 64 KB exactly
// -> 2 blocks/CU, 4 waves/SIMD. v_cvt_pk_bf16_f32 for all fp32->bf16 packing.
// 1024 blocks x 512 threads, 64-row tiles, wave tile 64x32 (fa=4, fb=2).

typedef __attribute__((ext_vector_type(8))) short s8v;           // 8 bf16 = 4 VGPR
typedef __attribute__((ext_vector_type(4))) float f32x4;
typedef __attribute__((ext_vector_type(4))) float f4v;
typedef __attribute__((ext_vector_type(4))) unsigned int u4v;

__device__ __forceinline__ float bf2f(unsigned short u) {
  union { unsigned int i; float f; } c; c.i = ((unsigned int)u) << 16; return c.f;
}
__device__ __forceinline__ unsigned short f2bf(float f) {
  union { float f; unsigned int i; } c; c.f = f;
  return (unsigned short)((c.i + 0x7fffu + ((c.i >> 16) & 1u)) >> 16);  // RNE
}
__device__ __forceinline__ unsigned int cvtpk(float lo, float hi) {   // bf16(lo) | bf16(hi)<<16
  unsigned int r;
  asm("v_cvt_pk_bf16_f32 %0, %1, %2" : "=v"(r) : "v"(lo), "v"(hi));
  return r;
}
__device__ __forceinline__ float sig_(float s)  { return 1.0f / (1.0f + __expf(-s)); }
__device__ __forceinline__ float tanh_(float s) { return 2.0f / (1.0f + __expf(-2.0f * s)) - 1.0f; }

// ---------------- weight prep: fp32 [K][N] -> bf16 fragment-major tiles ----------------
// Tile (nt, kt) = 16 n x 32 k = 512 shorts (1 KB), lane-major:
//   n = nt*16 + (lane&15), k = kt*32 + (lane>>4)*8 + e ; tile index t = nt*16 + kt.
// wzr: nt 0..15 = Wz/Uz, nt 16..31 = Wr/Ur (k<256 -> W, else U). whh: nt 0..15 = Wh/Uh.
__global__ void gru_prep(const float* __restrict__ Wz, const float* __restrict__ Uz,
                         const float* __restrict__ Wr, const float* __restrict__ Ur,
                         const float* __restrict__ Wh, const float* __restrict__ Uh,
                         unsigned short* __restrict__ wzr, unsigned short* __restrict__ whh) {
  int idx = blockIdx.x * 256 + threadIdx.x;
  if (idx < 512 * 512) {
    int t = idx >> 9, lane = (idx >> 3) & 63, e = idx & 7;
    int nt = t >> 4, kt = t & 15;
    int n = nt * 16 + (lane & 15);
    int k = kt * 32 + ((lane >> 4) << 3) + e;
    int nn = n & 255;
    float v;
    if (n < 256) v = (k < 256) ? Wz[k * 256 + nn] : Uz[(k - 256) * 256 + nn];
    else         v = (k < 256) ? Wr[k * 256 + nn] : Ur[(k - 256) * 256 + nn];
    wzr[idx] = f2bf(v);
  } else if (idx < 512 * 512 + 256 * 512) {
    int j = idx - 512 * 512;
    int t = j >> 9, lane = (j >> 3) & 63, e = j & 7;
    int nt = t >> 4, kt = t & 15;
    int n = nt * 16 + (lane & 15);
    int k = kt * 32 + ((lane >> 4) << 3) + e;
    float v = (k < 256) ? Wh[k * 256 + n] : Uh[(k - 256) * 256 + n];
    whh[j] = f2bf(v);
  }
}

#define MFMA(a, b, c) __builtin_amdgcn_mfma_f32_16x16x32_bf16((a), (b), (c), 0, 0, 0)

// ---- one K=256 half-sweep (8 groups): B 2-deep reg double-buffer, A from LDS ----
// Bt = weight base + tile offset + lane*8 (lane-adjusted). fb tile stride = 8192.
// Prefetch distance pinned to 1 group by sched_barrier fences (anti-hoist).
__device__ __forceinline__ void sweep8(f32x4 acc[4][2],
    const unsigned short* __restrict__ Bt,
    const unsigned short* A, int l15, int lg4)
{
  s8v bb[2][2];
  bb[0][0] = *(const s8v*)(Bt);
  bb[0][1] = *(const s8v*)(Bt + 8192);
#pragma unroll
  for (int g = 0; g < 8; ++g) {
    if (g < 7) {
      bb[(g + 1) & 1][0] = *(const s8v*)(Bt + (g + 1) * 512);
      bb[(g + 1) & 1][1] = *(const s8v*)(Bt + (g + 1) * 512 + 8192);
    }
    __builtin_amdgcn_sched_barrier(0);
    s8v af[4];
#pragma unroll
    for (int fa = 0; fa < 4; ++fa) {
      int row = fa * 16 + l15;
      int gp = (g * 4 + lg4) ^ (l15 & 7);
      af[fa] = *(const s8v*)(A + row * 256 + gp * 8);
    }
#pragma unroll
    for (int fa = 0; fa < 4; ++fa) {
      acc[fa][0] = MFMA(af[fa], bb[g & 1][0], acc[fa][0]);
      acc[fa][1] = MFMA(af[fa], bb[g & 1][1], acc[fa][1]);
    }
    __builtin_amdgcn_sched_barrier(0);
  }
}

// swizzled scalar LDS accessors (granule-XOR layout, matches sweep8 reads)
__device__ __forceinline__ float ldsA_get(const unsigned short* A, int row, int col) {
  int gp = ((col >> 3) ^ (row & 7));
  return bf2f(A[row * 256 + gp * 8 + (col & 7)]);
}
__device__ __forceinline__ void ldsA_put(unsigned short* A, int row, int col, unsigned short v) {
  int gp = ((col >> 3) ^ (row & 7));
  A[row * 256 + gp * 8 + (col & 7)] = v;
}

// ---------------- main fused kernel: 64 rows per block, 8 waves ----------------
__global__ __launch_bounds__(512, 4) void gru_main(
    const float* __restrict__ x, const float* __restrict__ hp,
    const unsigned short* __restrict__ wzr, const unsigned short* __restrict__ whh,
    const float* __restrict__ bz, const float* __restrict__ br, const float* __restrict__ bh,
    float* __restrict__ out)
{
  __shared__ __align__(16) unsigned short x_l[64 * 256];   // 32 KB, granule-XOR swizzled
  __shared__ __align__(16) unsigned short h_l[64 * 256];   // 32 KB  -> 64 KB total, 2 blocks/CU

  const int tid = threadIdx.x;
  const int lane = tid & 63;
  const int wv = tid >> 6;                   // 0..7 : wave's 32-col slice
  const int l15 = lane & 15, lg4 = lane >> 4;
  const int blk = blockIdx.x;
  const int row0 = blk * 64;

  const unsigned short* Bz = wzr + wv * 16384 + lane * 8;            // z: nt = wv*2
  const unsigned short* Br = wzr + 131072 + wv * 16384 + lane * 8;   // r: nt = wv*2+16
  const unsigned short* Bh = whh + wv * 16384 + lane * 8;            // h

  // ---- stage x, h tiles to LDS (fp32 -> bf16 via cvt_pk), granule-XOR layout
  {
    const int srow = tid >> 3;               // 0..63
    const int part = tid & 7;                // 4 granules each
    const float* xs = x  + (size_t)(row0 + srow) * 256 + part * 32;
    const float* hs = hp + (size_t)(row0 + srow) * 256 + part * 32;
    unsigned short* xd = x_l + srow * 256;
    unsigned short* hd = h_l + srow * 256;
    const int r7 = srow & 7;
#pragma unroll
    for (int j = 0; j < 4; ++j) {
      int gp = (part * 4 + j) ^ r7;
      f4v v0 = *(const f4v*)(xs + j * 8);
      f4v v1 = *(const f4v*)(xs + j * 8 + 4);
      u4v o = (u4v){ cvtpk(v0[0], v0[1]), cvtpk(v0[2], v0[3]),
                     cvtpk(v1[0], v1[1]), cvtpk(v1[2], v1[3]) };
      *(u4v*)(xd + gp * 8) = o;
    }
#pragma unroll
    for (int j = 0; j < 4; ++j) {
      int gp = (part * 4 + j) ^ r7;
      f4v v0 = *(const f4v*)(hs + j * 8);
      f4v v1 = *(const f4v*)(hs + j * 8 + 4);
      u4v o = (u4v){ cvtpk(v0[0], v0[1]), cvtpk(v0[2], v0[3]),
                     cvtpk(v1[0], v1[1]), cvtpk(v1[2], v1[3]) };
      *(u4v*)(hd + gp * 8) = o;
    }
  }
  __syncthreads();

  f32x4 acc[4][2];
  unsigned int zp[4][2][2];    // z gate, packed bf16   : 16 VGPR
  unsigned int rhp[4][2][2];   // r*h_prev, packed bf16 : 16 VGPR

  // ===== PASS z: z = sigmoid(x Wz + h Uz + bz) -> zp
#pragma unroll
  for (int fa = 0; fa < 4; ++fa)
#pragma unroll
    for (int fb = 0; fb < 2; ++fb) acc[fa][fb] = (f32x4){0.f,0.f,0.f,0.f};
  sweep8(acc, Bz,        x_l, l15, lg4);
  sweep8(acc, Bz + 4096, h_l, l15, lg4);     // kt 8..15
#pragma unroll
  for (int fb = 0; fb < 2; ++fb) {
    float bv = bz[wv * 32 + fb * 16 + l15];
#pragma unroll
    for (int fa = 0; fa < 4; ++fa) {
      f32x4 a = acc[fa][fb];
#pragma unroll
      for (int p = 0; p < 2; ++p)
        zp[fa][fb][p] = cvtpk(sig_(a[2*p] + bv), sig_(a[2*p+1] + bv));
    }
  }

  // ===== PASS r: r = sigmoid(x Wr + h Ur + br); rh = r*h_prev -> rhp
#pragma unroll
  for (int fa = 0; fa < 4; ++fa)
#pragma unroll
    for (int fb = 0; fb < 2; ++fb) acc[fa][fb] = (f32x4){0.f,0.f,0.f,0.f};
  sweep8(acc, Br,        x_l, l15, lg4);
  sweep8(acc, Br + 4096, h_l, l15, lg4);
#pragma unroll
  for (int fb = 0; fb < 2; ++fb) {
    const int col = wv * 32 + fb * 16 + l15;
    const float bv = br[col];
#pragma unroll
    for (int fa = 0; fa < 4; ++fa) {
      f32x4 a = acc[fa][fb];
#pragma unroll
      for (int p = 0; p < 2; ++p) {
        const int row = fa * 16 + lg4 * 4 + 2 * p;
        float r0 = sig_(a[2*p]   + bv);
        float r1 = sig_(a[2*p+1] + bv);
        float h0 = ldsA_get(h_l, row,     col);
        float h1 = ldsA_get(h_l, row + 1, col);
        rhp[fa][fb][p] = cvtpk(r0 * h0, r1 * h1);
      }
    }
  }

  // ===== PASS h: h_hat = tanh(x Wh + rh Uh + bh)
#pragma unroll
  for (int fa = 0; fa < 4; ++fa)
#pragma unroll
    for (int fb = 0; fb < 2; ++fb) acc[fa][fb] = (f32x4){0.f,0.f,0.f,0.f};
  sweep8(acc, Bh, x_l, l15, lg4);            // x half (x_l still valid)

  __syncthreads();                           // all waves done reading x_l
#pragma unroll
  for (int fb = 0; fb < 2; ++fb) {           // overwrite x_l with rh
    const int col = wv * 32 + fb * 16 + l15;
#pragma unroll
    for (int fa = 0; fa < 4; ++fa)
#pragma unroll
      for (int p = 0; p < 2; ++p) {
        const int row = fa * 16 + lg4 * 4 + 2 * p;
        unsigned int w = rhp[fa][fb][p];
        ldsA_put(x_l, row,     col, (unsigned short)(w & 0xffffu));
        ldsA_put(x_l, row + 1, col, (unsigned short)(w >> 16));
      }
  }
  __syncthreads();                           // rh visible

  sweep8(acc, Bh + 4096, x_l, l15, lg4);     // rh half (kt 8..15)

  // ===== epilogue: h = z*h_prev + (1-z)*h_hat
#pragma unroll
  for (int fb = 0; fb < 2; ++fb) {
    const int col = wv * 32 + fb * 16 + l15;
    const float bv = bh[col];
#pragma unroll
    for (int fa = 0; fa < 4; ++fa) {
      f32x4 a = acc[fa][fb];
#pragma unroll
      for (int i = 0; i < 4; ++i) {
        const int row = fa * 16 + lg4 * 4 + i;
        float hh = tanh_(a[i] + bv);
        unsigned int zw = zp[fa][fb][i >> 1];
        float z = bf2f((unsigned short)((i & 1) ? (zw >> 16) : (zw & 0xffffu)));
        float hv = ldsA_get(h_l, row, col);
        out[(size_t)(row0 + row) * 256 + col] = z * hv + (1.0f - z) * hh;
      }
    }
  }
}

extern "C" void kernel_launch(void* const* d_in, const int* in_sizes, int n_in,
                              void* d_out, int out_size, void* d_ws, size_t ws_size,
                              hipStream_t stream) {
  const float* x  = (const float*)d_in[0];
  const float* hp = (const float*)d_in[1];
  const float* Wz = (const float*)d_in[2];
  const float* Uz = (const float*)d_in[3];
  const float* bz = (const float*)d_in[4];
  const float* Wr = (const float*)d_in[5];
  const float* Ur = (const float*)d_in[6];
  const float* br = (const float*)d_in[7];
  const float* Wh = (const float*)d_in[8];
  const float* Uh = (const float*)d_in[9];
  const float* bh = (const float*)d_in[10];

  if (ws_size < (size_t)(512 * 512 + 256 * 512) * sizeof(unsigned short)) return;  // need 768 KB

  unsigned short* wzr = (unsigned short*)d_ws;
  unsigned short* whh = wzr + 512 * 512;

  gru_prep<<<1536, 256, 0, stream>>>(Wz, Uz, Wr, Ur, Wh, Uh, wzr, whh);
  gru_main<<<1024, 512, 0, stream>>>(x, hp, wzr, whh, bz, br, bh, (float*)d_out);
}